// Round 5
// baseline (156.265 us; speedup 1.0000x reference)
//
#include <hip/hip_runtime.h>

#define N 64
#define NPAD 65          // bank = (row+col)%32 -> conflict-free row AND col b32 access
#define ITERS 50
#define TEMP 12.5f
#define WEPS 1e-5f
#define QDIM 75
#define WDIM 5

__device__ __forceinline__ float waveReduceSum(float x) {
#pragma unroll
    for (int off = 32; off; off >>= 1) x += __shfl_xor(x, off, 64);
    return x;
}

// TWO independent Sinkhorn problems per wave: 750 waves total (<1024 SIMDs, all
// concurrent) and two independent dependency chains per wave so each problem's
// LDS-broadcast latency hides under the other's FMA stream. ~300 VGPRs needed;
// waves_per_eu=1 gives the full 512 budget (occupancy is problem-count-bound).
__global__ __launch_bounds__(64, 1) void emd_sinkhorn2(
    const float* __restrict__ sim,   // [B, 64, 64]
    const float* __restrict__ w1,    // [B, N]
    const float* __restrict__ w2,    // [E, W, Q, N] (transposed Q/W)
    float* __restrict__ out,         // [B]
    int B)
{
    __shared__ float S0[N * NPAD];
    __shared__ float S1[N * NPAD];
    __shared__ __align__(16) float U0[N], V0[N], U1[N], V1[N];

    const int lane = threadIdx.x;
    const int b0 = blockIdx.x * 2;
    const int b1e = b0 + 1;
    const int b1 = (b1e < B) ? b1e : b0;   // defensive (B=1500 is even)

    // ---- stage both sim matrices into LDS (coalesced float4) ----
    {
        const float4* g40 = (const float4*)(sim + (size_t)b0 * N * N);
        const float4* g41 = (const float4*)(sim + (size_t)b1 * N * N);
#pragma unroll
        for (int t = 0; t < 16; ++t) {
            float4 x = g40[t * 64 + lane];
            float4 y = g41[t * 64 + lane];
            int idx = t * 64 + lane;
            int r = idx >> 4;
            int c = (idx & 15) * 4;
            S0[r * NPAD + c + 0] = x.x;  S0[r * NPAD + c + 1] = x.y;
            S0[r * NPAD + c + 2] = x.z;  S0[r * NPAD + c + 3] = x.w;
            S1[r * NPAD + c + 0] = y.x;  S1[r * NPAD + c + 1] = y.y;
            S1[r * NPAD + c + 2] = y.z;  S1[r * NPAD + c + 3] = y.w;
        }
    }
    __syncthreads();

    // ---- K = exp(20*(sim-1)): row(lane) + col(lane) fragments, both problems ----
    float K0r[N], K0c[N], K1r[N], K1c[N];
#pragma unroll
    for (int j = 0; j < N; ++j) {
        K0r[j] = __expf((S0[lane * NPAD + j] - 1.0f) * 20.0f);
        K1r[j] = __expf((S1[lane * NPAD + j] - 1.0f) * 20.0f);
    }
#pragma unroll
    for (int i = 0; i < N; ++i) {
        K0c[i] = __expf((S0[i * NPAD + lane] - 1.0f) * 20.0f);
        K1c[i] = __expf((S1[i * NPAD + lane] - 1.0f) * 20.0f);
    }
    // opaque pin: cannot be duplicated/rematerialized into the loop
#pragma unroll
    for (int j = 0; j < N; ++j) {
        asm volatile("" : "+v"(K0r[j]));
        asm volatile("" : "+v"(K0c[j]));
        asm volatile("" : "+v"(K1r[j]));
        asm volatile("" : "+v"(K1c[j]));
    }

    // ---- marginals ----
    float a0 = w1[(size_t)b0 * N + lane];
    a0 = fmaxf(a0, 0.0f) + WEPS;
    a0 *= (float)N / waveReduceSum(a0);
    float a1 = w1[(size_t)b1 * N + lane];
    a1 = fmaxf(a1, 0.0f) + WEPS;
    a1 *= (float)N / waveReduceSum(a1);

    int e = b0 / (QDIM * WDIM), rem = b0 % (QDIM * WDIM);
    int q = rem / WDIM, w = rem % WDIM;
    float g0 = w2[((((size_t)e * WDIM + w) * QDIM) + q) * N + lane];
    g0 = fmaxf(g0, 0.0f) + WEPS;
    g0 *= (float)N / waveReduceSum(g0);

    e = b1 / (QDIM * WDIM); rem = b1 % (QDIM * WDIM);
    q = rem / WDIM; w = rem % WDIM;
    float g1 = w2[((((size_t)e * WDIM + w) * QDIM) + q) * N + lane];
    g1 = fmaxf(g1, 0.0f) + WEPS;
    g1 *= (float)N / waveReduceSum(g1);

    V0[lane] = 1.0f;
    V1[lane] = 1.0f;
    __syncthreads();

    float u0 = 0.0f, u1 = 0.0f;
#pragma unroll 1
    for (int it = 0; it < ITERS; ++it) {
        // ---- u = a / (K v), both problems interleaved ----
        {
            const float4* A4 = (const float4*)V0;
            const float4* B4 = (const float4*)V1;
            float p0 = 0, p1 = 0, p2 = 0, p3 = 0, p4 = 0, p5 = 0, p6 = 0, p7 = 0;
            float r0 = 0, r1 = 0, r2 = 0, r3 = 0, r4 = 0, r5 = 0, r6 = 0, r7 = 0;
#pragma unroll
            for (int j8 = 0; j8 < 8; ++j8) {
                float4 x0 = A4[2 * j8], x1 = A4[2 * j8 + 1];
                float4 y0 = B4[2 * j8], y1 = B4[2 * j8 + 1];
                p0 = fmaf(K0r[8 * j8 + 0], x0.x, p0);  r0 = fmaf(K1r[8 * j8 + 0], y0.x, r0);
                p1 = fmaf(K0r[8 * j8 + 1], x0.y, p1);  r1 = fmaf(K1r[8 * j8 + 1], y0.y, r1);
                p2 = fmaf(K0r[8 * j8 + 2], x0.z, p2);  r2 = fmaf(K1r[8 * j8 + 2], y0.z, r2);
                p3 = fmaf(K0r[8 * j8 + 3], x0.w, p3);  r3 = fmaf(K1r[8 * j8 + 3], y0.w, r3);
                p4 = fmaf(K0r[8 * j8 + 4], x1.x, p4);  r4 = fmaf(K1r[8 * j8 + 4], y1.x, r4);
                p5 = fmaf(K0r[8 * j8 + 5], x1.y, p5);  r5 = fmaf(K1r[8 * j8 + 5], y1.y, r5);
                p6 = fmaf(K0r[8 * j8 + 6], x1.z, p6);  r6 = fmaf(K1r[8 * j8 + 6], y1.z, r6);
                p7 = fmaf(K0r[8 * j8 + 7], x1.w, p7);  r7 = fmaf(K1r[8 * j8 + 7], y1.w, r7);
            }
            u0 = a0 * __builtin_amdgcn_rcpf(((p0 + p1) + (p2 + p3)) + ((p4 + p5) + (p6 + p7)));
            u1 = a1 * __builtin_amdgcn_rcpf(((r0 + r1) + (r2 + r3)) + ((r4 + r5) + (r6 + r7)));
            U0[lane] = u0;
            U1[lane] = u1;
        }
        __syncthreads();

        // ---- v = b / (K^T u), both problems interleaved ----
        {
            const float4* A4 = (const float4*)U0;
            const float4* B4 = (const float4*)U1;
            float p0 = 0, p1 = 0, p2 = 0, p3 = 0, p4 = 0, p5 = 0, p6 = 0, p7 = 0;
            float r0 = 0, r1 = 0, r2 = 0, r3 = 0, r4 = 0, r5 = 0, r6 = 0, r7 = 0;
#pragma unroll
            for (int i8 = 0; i8 < 8; ++i8) {
                float4 x0 = A4[2 * i8], x1 = A4[2 * i8 + 1];
                float4 y0 = B4[2 * i8], y1 = B4[2 * i8 + 1];
                p0 = fmaf(K0c[8 * i8 + 0], x0.x, p0);  r0 = fmaf(K1c[8 * i8 + 0], y0.x, r0);
                p1 = fmaf(K0c[8 * i8 + 1], x0.y, p1);  r1 = fmaf(K1c[8 * i8 + 1], y0.y, r1);
                p2 = fmaf(K0c[8 * i8 + 2], x0.z, p2);  r2 = fmaf(K1c[8 * i8 + 2], y0.z, r2);
                p3 = fmaf(K0c[8 * i8 + 3], x0.w, p3);  r3 = fmaf(K1c[8 * i8 + 3], y0.w, r3);
                p4 = fmaf(K0c[8 * i8 + 4], x1.x, p4);  r4 = fmaf(K1c[8 * i8 + 4], y1.x, r4);
                p5 = fmaf(K0c[8 * i8 + 5], x1.y, p5);  r5 = fmaf(K1c[8 * i8 + 5], y1.y, r5);
                p6 = fmaf(K0c[8 * i8 + 6], x1.z, p6);  r6 = fmaf(K1c[8 * i8 + 6], y1.z, r6);
                p7 = fmaf(K0c[8 * i8 + 7], x1.w, p7);  r7 = fmaf(K1c[8 * i8 + 7], y1.w, r7);
            }
            float v0 = g0 * __builtin_amdgcn_rcpf(((p0 + p1) + (p2 + p3)) + ((p4 + p5) + (p6 + p7)));
            float v1 = g1 * __builtin_amdgcn_rcpf(((r0 + r1) + (r2 + r3)) + ((r4 + r5) + (r6 + r7)));
            V0[lane] = v0;
            V1[lane] = v1;
        }
        __syncthreads();
    }

    // ---- score = sum_ij u_i K_ij v_j sim_ij for both problems ----
    float s0 = 0, s1 = 0, s2 = 0, s3 = 0;
    float t0 = 0, t1 = 0, t2 = 0, t3 = 0;
#pragma unroll
    for (int j4 = 0; j4 < 16; ++j4) {
        float4 x = ((const float4*)V0)[j4];
        float4 y = ((const float4*)V1)[j4];
        s0 = fmaf(K0r[4 * j4 + 0] * S0[lane * NPAD + 4 * j4 + 0], x.x, s0);
        s1 = fmaf(K0r[4 * j4 + 1] * S0[lane * NPAD + 4 * j4 + 1], x.y, s1);
        s2 = fmaf(K0r[4 * j4 + 2] * S0[lane * NPAD + 4 * j4 + 2], x.z, s2);
        s3 = fmaf(K0r[4 * j4 + 3] * S0[lane * NPAD + 4 * j4 + 3], x.w, s3);
        t0 = fmaf(K1r[4 * j4 + 0] * S1[lane * NPAD + 4 * j4 + 0], y.x, t0);
        t1 = fmaf(K1r[4 * j4 + 1] * S1[lane * NPAD + 4 * j4 + 1], y.y, t1);
        t2 = fmaf(K1r[4 * j4 + 2] * S1[lane * NPAD + 4 * j4 + 2], y.z, t2);
        t3 = fmaf(K1r[4 * j4 + 3] * S1[lane * NPAD + 4 * j4 + 3], y.w, t3);
    }
    float tot0 = waveReduceSum(u0 * ((s0 + s1) + (s2 + s3)));
    float tot1 = waveReduceSum(u1 * ((t0 + t1) + (t2 + t3)));
    if (lane == 0) {
        out[b0] = tot0 * (TEMP / (float)N);
        if (b1e < B) out[b1e] = tot1 * (TEMP / (float)N);
    }
}

extern "C" void kernel_launch(void* const* d_in, const int* in_sizes, int n_in,
                              void* d_out, int out_size, void* d_ws, size_t ws_size,
                              hipStream_t stream) {
    const float* sim = (const float*)d_in[0];
    const float* w1  = (const float*)d_in[1];
    const float* w2  = (const float*)d_in[2];
    float* out       = (float*)d_out;
    const int B = in_sizes[0] / (N * N);        // 1500
    const int nb = (B + 1) / 2;                 // 750 blocks, 2 problems each
    emd_sinkhorn2<<<nb, 64, 0, stream>>>(sim, w1, w2, out, B);
}

// Round 6
// 113.706 us; speedup vs baseline: 1.3743x; 1.3743x over previous
//
#include <hip/hip_runtime.h>

#define N 64
#define NPAD 65          // bank=(row+col)%32: row AND col b32 access ≤2-way (free, m136)
#define ITERS 50
#define TEMP 12.5f
#define WEPS 1e-5f
#define QDIM 75
#define WDIM 5

__device__ __forceinline__ float waveReduceSum(float x) {
#pragma unroll
    for (int off = 32; off; off >>= 1) x += __shfl_xor(x, off, 64);
    return x;
}

// 4 waves per problem. Thread t owns row r=t>>2 (u-phase) and col r (v-phase)
// with 16-element K fragments (segment (t&3)*16). Per phase: 4 ds_read_b128 +
// 16 FMA + 4-lane shfl reduce + rcp. 6000 waves total -> ~5.9 waves/SIMD TLP.
__global__ __launch_bounds__(256, 1) void emd_sinkhorn4w(
    const float* __restrict__ sim,   // [B, 64, 64]
    const float* __restrict__ w1,    // [B, N]
    const float* __restrict__ w2,    // [E, W, Q, N] (transposed Q/W)
    float* __restrict__ out,         // [B]
    int B)
{
    __shared__ float S[N * NPAD];
    __shared__ __align__(16) float U[N], V[N], A[N], Bm[N];
    __shared__ float Wred[4];

    const int t    = threadIdx.x;
    const int lane = t & 63;
    const int wv   = t >> 6;
    const int b    = blockIdx.x;
    const int r    = t >> 2;       // row (u-phase) / col (v-phase) of this 4-group
    const int j4   = t & 3;
    const int c0   = j4 * 16;      // 16-element segment base

    // ---- stage sim into padded LDS (coalesced float4) ----
    const float4* g4 = (const float4*)(sim + (size_t)b * N * N);
#pragma unroll
    for (int q = 0; q < 4; ++q) {
        int idx = q * 256 + t;
        float4 x = g4[idx];
        int rr = idx >> 4;
        int cc = (idx & 15) * 4;
        S[rr * NPAD + cc + 0] = x.x;
        S[rr * NPAD + cc + 1] = x.y;
        S[rr * NPAD + cc + 2] = x.z;
        S[rr * NPAD + cc + 3] = x.w;
    }
    // ---- marginals (waves 0/1) + V init (wave 2), concurrent with staging ----
    if (wv == 0) {
        float a = w1[(size_t)b * N + lane];
        a = fmaxf(a, 0.0f) + WEPS;
        a *= (float)N / waveReduceSum(a);
        A[lane] = a;
    } else if (wv == 1) {
        const int e  = b / (QDIM * WDIM);
        const int rm = b % (QDIM * WDIM);
        const int q  = rm / WDIM, w = rm % WDIM;
        float g = w2[((((size_t)e * WDIM + w) * QDIM) + q) * N + lane];
        g = fmaxf(g, 0.0f) + WEPS;
        g *= (float)N / waveReduceSum(g);
        Bm[lane] = g;
    } else if (wv == 2) {
        V[lane] = 1.0f;
    }
    __syncthreads();

    // ---- 16-element K fragments: Kr = K[r][c0+k], Kc = K[c0+k][r] ----
    // K = exp(-cost/eps) = exp(20*(sim-1))
    float Kr[16], Kc[16];
#pragma unroll
    for (int k = 0; k < 16; ++k) {
        Kr[k] = __expf((S[r * NPAD + c0 + k] - 1.0f) * 20.0f);
        Kc[k] = __expf((S[(c0 + k) * NPAD + r] - 1.0f) * 20.0f);
    }
    const float a_reg = A[r];
    const float b_reg = Bm[r];

    float u = 0.0f;
#pragma unroll 1
    for (int it = 0; it < ITERS; ++it) {
        // ---- u[r] = a[r] / sum_c K[r][c] v[c] ----
        {
            const float4* V4 = (const float4*)(V + c0);
            float4 x0 = V4[0], x1 = V4[1], x2 = V4[2], x3 = V4[3];
            float p0 = 0, p1 = 0, p2 = 0, p3 = 0;
            p0 = fmaf(Kr[ 0], x0.x, p0); p1 = fmaf(Kr[ 1], x0.y, p1);
            p2 = fmaf(Kr[ 2], x0.z, p2); p3 = fmaf(Kr[ 3], x0.w, p3);
            p0 = fmaf(Kr[ 4], x1.x, p0); p1 = fmaf(Kr[ 5], x1.y, p1);
            p2 = fmaf(Kr[ 6], x1.z, p2); p3 = fmaf(Kr[ 7], x1.w, p3);
            p0 = fmaf(Kr[ 8], x2.x, p0); p1 = fmaf(Kr[ 9], x2.y, p1);
            p2 = fmaf(Kr[10], x2.z, p2); p3 = fmaf(Kr[11], x2.w, p3);
            p0 = fmaf(Kr[12], x3.x, p0); p1 = fmaf(Kr[13], x3.y, p1);
            p2 = fmaf(Kr[14], x3.z, p2); p3 = fmaf(Kr[15], x3.w, p3);
            float s = (p0 + p1) + (p2 + p3);
            s += __shfl_xor(s, 1, 64);   // reduce over the 4-lane row group
            s += __shfl_xor(s, 2, 64);
            u = a_reg * __builtin_amdgcn_rcpf(s);
            if (j4 == 0) U[r] = u;
        }
        __syncthreads();

        // ---- v[r] = b[r] / sum_i K[i][r] u[i] ----
        {
            const float4* U4 = (const float4*)(U + c0);
            float4 x0 = U4[0], x1 = U4[1], x2 = U4[2], x3 = U4[3];
            float p0 = 0, p1 = 0, p2 = 0, p3 = 0;
            p0 = fmaf(Kc[ 0], x0.x, p0); p1 = fmaf(Kc[ 1], x0.y, p1);
            p2 = fmaf(Kc[ 2], x0.z, p2); p3 = fmaf(Kc[ 3], x0.w, p3);
            p0 = fmaf(Kc[ 4], x1.x, p0); p1 = fmaf(Kc[ 5], x1.y, p1);
            p2 = fmaf(Kc[ 6], x1.z, p2); p3 = fmaf(Kc[ 7], x1.w, p3);
            p0 = fmaf(Kc[ 8], x2.x, p0); p1 = fmaf(Kc[ 9], x2.y, p1);
            p2 = fmaf(Kc[10], x2.z, p2); p3 = fmaf(Kc[11], x2.w, p3);
            p0 = fmaf(Kc[12], x3.x, p0); p1 = fmaf(Kc[13], x3.y, p1);
            p2 = fmaf(Kc[14], x3.z, p2); p3 = fmaf(Kc[15], x3.w, p3);
            float s = (p0 + p1) + (p2 + p3);
            s += __shfl_xor(s, 1, 64);
            s += __shfl_xor(s, 2, 64);
            float v = b_reg * __builtin_amdgcn_rcpf(s);
            if (j4 == 0) V[r] = v;
        }
        __syncthreads();
    }

    // ---- score = sum_ij u_i K_ij v_j sim_ij ----
    // thread t: row r, cols c0..c0+15 (each (i,j) covered exactly once)
    {
        const float4* V4 = (const float4*)(V + c0);
        float4 x0 = V4[0], x1 = V4[1], x2 = V4[2], x3 = V4[3];
        float p0 = 0, p1 = 0, p2 = 0, p3 = 0;
        const float* Srow = S + r * NPAD + c0;
        p0 = fmaf(Kr[ 0] * Srow[ 0], x0.x, p0); p1 = fmaf(Kr[ 1] * Srow[ 1], x0.y, p1);
        p2 = fmaf(Kr[ 2] * Srow[ 2], x0.z, p2); p3 = fmaf(Kr[ 3] * Srow[ 3], x0.w, p3);
        p0 = fmaf(Kr[ 4] * Srow[ 4], x1.x, p0); p1 = fmaf(Kr[ 5] * Srow[ 5], x1.y, p1);
        p2 = fmaf(Kr[ 6] * Srow[ 6], x1.z, p2); p3 = fmaf(Kr[ 7] * Srow[ 7], x1.w, p3);
        p0 = fmaf(Kr[ 8] * Srow[ 8], x2.x, p0); p1 = fmaf(Kr[ 9] * Srow[ 9], x2.y, p1);
        p2 = fmaf(Kr[10] * Srow[10], x2.z, p2); p3 = fmaf(Kr[11] * Srow[11], x2.w, p3);
        p0 = fmaf(Kr[12] * Srow[12], x3.x, p0); p1 = fmaf(Kr[13] * Srow[13], x3.y, p1);
        p2 = fmaf(Kr[14] * Srow[14], x3.z, p2); p3 = fmaf(Kr[15] * Srow[15], x3.w, p3);
        float part = u * ((p0 + p1) + (p2 + p3));
        float ws = waveReduceSum(part);
        if (lane == 0) Wred[wv] = ws;
    }
    __syncthreads();
    if (t == 0)
        out[b] = (Wred[0] + Wred[1] + Wred[2] + Wred[3]) * (TEMP / (float)N);
}

extern "C" void kernel_launch(void* const* d_in, const int* in_sizes, int n_in,
                              void* d_out, int out_size, void* d_ws, size_t ws_size,
                              hipStream_t stream) {
    const float* sim = (const float*)d_in[0];
    const float* w1  = (const float*)d_in[1];
    const float* w2  = (const float*)d_in[2];
    float* out       = (float*)d_out;
    const int B = in_sizes[0] / (N * N);   // 1500
    emd_sinkhorn4w<<<B, 256, 0, stream>>>(sim, w1, w2, out, B);
}

// Round 7
// 101.785 us; speedup vs baseline: 1.5353x; 1.1171x over previous
//
#include <hip/hip_runtime.h>

#define N 64
#define ITERS 50
#define TEMP 12.5f
#define WEPS 1e-5f
#define QDIM 75
#define WDIM 5

// quad_perm DPP: butterfly within aligned 4-lane quads (pure VALU pipe, no LDS)
#define DPP_XOR1(x) __int_as_float(__builtin_amdgcn_update_dpp(0, __float_as_int(x), 0xB1, 0xF, 0xF, true))
#define DPP_XOR2(x) __int_as_float(__builtin_amdgcn_update_dpp(0, __float_as_int(x), 0x4E, 0xF, 0xF, true))

__device__ __forceinline__ float waveReduceSum(float x) {
#pragma unroll
    for (int off = 32; off; off >>= 1) x += __shfl_xor(x, off, 64);
    return x;
}

// One wave per problem. Lane L = 4g+s owns a 4x16 tile of K: rows 4g..4g+3,
// cols 16s..16s+15 (and the transposed tile for the K^T phase). Each v-value
// read from LDS feeds 4 rows -> LDS volume per matvec = 4KB (was 16KB, the
// R1-R6 invariant wall). Quad-reduce via DPP (VALU pipe). LDS holds only
// U[64] + V[64] = 512B. Lane L outputs row/col L (4g+s == L).
__global__ __launch_bounds__(64, 1) void emd_tile(
    const float* __restrict__ sim,   // [B, 64, 64]
    const float* __restrict__ w1,    // [B, N]
    const float* __restrict__ w2,    // [E, W, Q, N] (transposed Q/W)
    float* __restrict__ out,         // [B]
    int B)
{
    __shared__ __align__(16) float S[128];   // S[0..63] = U, S[64..127] = V

    const int lane = threadIdx.x;
    const int b    = blockIdx.x;
    const int g    = lane >> 2;      // row-group base 4g
    const int s    = lane & 3;       // col-segment base 16s
    const float* gm = sim + (size_t)b * N * N;

    // ---- K fragments straight from global (16KB matrix, L1/L2 resident) ----
    // Kr[k][j] = K[4g+k][16s+j],  Kc[k][j] = K[16s+j][4g+k],  K=exp(20*(sim-1))
    float Kr[4][16], Kc[4][16];
#pragma unroll
    for (int k = 0; k < 4; ++k)
#pragma unroll
        for (int m = 0; m < 4; ++m) {
            float4 x = *(const float4*)(gm + (4 * g + k) * N + 16 * s + 4 * m);
            Kr[k][4 * m + 0] = __expf((x.x - 1.0f) * 20.0f);
            Kr[k][4 * m + 1] = __expf((x.y - 1.0f) * 20.0f);
            Kr[k][4 * m + 2] = __expf((x.z - 1.0f) * 20.0f);
            Kr[k][4 * m + 3] = __expf((x.w - 1.0f) * 20.0f);
        }
#pragma unroll
    for (int j = 0; j < 16; ++j) {
        float4 x = *(const float4*)(gm + (16 * s + j) * N + 4 * g);
        Kc[0][j] = __expf((x.x - 1.0f) * 20.0f);
        Kc[1][j] = __expf((x.y - 1.0f) * 20.0f);
        Kc[2][j] = __expf((x.z - 1.0f) * 20.0f);
        Kc[3][j] = __expf((x.w - 1.0f) * 20.0f);
    }
    // opaque pin: block remat/sinking of the exp chains into the loop
#pragma unroll
    for (int k = 0; k < 4; ++k)
#pragma unroll
        for (int j = 0; j < 16; ++j) {
            asm volatile("" : "+v"(Kr[k][j]));
            asm volatile("" : "+v"(Kc[k][j]));
        }

    // ---- marginals: each lane needs only its OWN row/col value ----
    float a_own = w1[(size_t)b * N + lane];
    a_own = fmaxf(a_own, 0.0f) + WEPS;
    a_own *= (float)N / waveReduceSum(a_own);

    const int e  = b / (QDIM * WDIM);
    const int rm = b % (QDIM * WDIM);
    const int q  = rm / WDIM, w = rm % WDIM;
    float b_own = w2[((((size_t)e * WDIM + w) * QDIM) + q) * N + lane];
    b_own = fmaxf(b_own, 0.0f) + WEPS;
    b_own *= (float)N / waveReduceSum(b_own);

    S[64 + lane] = 1.0f;   // V init (log_v = 0)
    __syncthreads();

#pragma unroll 1
    for (int it = 0; it < ITERS; ++it) {
        // ---- u-phase: u[r] = a[r]/sum_c K[r][c] v[c]; lane outputs row=lane ----
        {
            const float4* V4 = (const float4*)&S[64 + 16 * s];
            float4 x0 = V4[0], x1 = V4[1], x2 = V4[2], x3 = V4[3];
            float acc0 = 0, acc1 = 0, acc2 = 0, acc3 = 0;
#define ROWF(k, acc)                                                        \
            acc = fmaf(Kr[k][ 0], x0.x, acc); acc = fmaf(Kr[k][ 1], x0.y, acc); \
            acc = fmaf(Kr[k][ 2], x0.z, acc); acc = fmaf(Kr[k][ 3], x0.w, acc); \
            acc = fmaf(Kr[k][ 4], x1.x, acc); acc = fmaf(Kr[k][ 5], x1.y, acc); \
            acc = fmaf(Kr[k][ 6], x1.z, acc); acc = fmaf(Kr[k][ 7], x1.w, acc); \
            acc = fmaf(Kr[k][ 8], x2.x, acc); acc = fmaf(Kr[k][ 9], x2.y, acc); \
            acc = fmaf(Kr[k][10], x2.z, acc); acc = fmaf(Kr[k][11], x2.w, acc); \
            acc = fmaf(Kr[k][12], x3.x, acc); acc = fmaf(Kr[k][13], x3.y, acc); \
            acc = fmaf(Kr[k][14], x3.z, acc); acc = fmaf(Kr[k][15], x3.w, acc)
            ROWF(0, acc0); ROWF(1, acc1); ROWF(2, acc2); ROWF(3, acc3);
            // quad butterfly (DPP): every lane gets all 4 row-sums of its quad
            acc0 += DPP_XOR1(acc0); acc1 += DPP_XOR1(acc1);
            acc2 += DPP_XOR1(acc2); acc3 += DPP_XOR1(acc3);
            acc0 += DPP_XOR2(acc0); acc1 += DPP_XOR2(acc1);
            acc2 += DPP_XOR2(acc2); acc3 += DPP_XOR2(acc3);
            // lane's own row = 4g+s -> pick acc[s]
            float ab = (s & 1) ? acc1 : acc0;
            float cd = (s & 1) ? acc3 : acc2;
            float se = (s & 2) ? cd : ab;
            S[lane] = a_own * __builtin_amdgcn_rcpf(se);   // U[lane]
        }
        __syncthreads();

        // ---- v-phase: v[c] = b[c]/sum_i K[i][c] u[i]; lane outputs col=lane ----
        {
            const float4* U4 = (const float4*)&S[16 * s];
            float4 x0 = U4[0], x1 = U4[1], x2 = U4[2], x3 = U4[3];
            float acc0 = 0, acc1 = 0, acc2 = 0, acc3 = 0;
#define COLF(k, acc)                                                        \
            acc = fmaf(Kc[k][ 0], x0.x, acc); acc = fmaf(Kc[k][ 1], x0.y, acc); \
            acc = fmaf(Kc[k][ 2], x0.z, acc); acc = fmaf(Kc[k][ 3], x0.w, acc); \
            acc = fmaf(Kc[k][ 4], x1.x, acc); acc = fmaf(Kc[k][ 5], x1.y, acc); \
            acc = fmaf(Kc[k][ 6], x1.z, acc); acc = fmaf(Kc[k][ 7], x1.w, acc); \
            acc = fmaf(Kc[k][ 8], x2.x, acc); acc = fmaf(Kc[k][ 9], x2.y, acc); \
            acc = fmaf(Kc[k][10], x2.z, acc); acc = fmaf(Kc[k][11], x2.w, acc); \
            acc = fmaf(Kc[k][12], x3.x, acc); acc = fmaf(Kc[k][13], x3.y, acc); \
            acc = fmaf(Kc[k][14], x3.z, acc); acc = fmaf(Kc[k][15], x3.w, acc)
            COLF(0, acc0); COLF(1, acc1); COLF(2, acc2); COLF(3, acc3);
            acc0 += DPP_XOR1(acc0); acc1 += DPP_XOR1(acc1);
            acc2 += DPP_XOR1(acc2); acc3 += DPP_XOR1(acc3);
            acc0 += DPP_XOR2(acc0); acc1 += DPP_XOR2(acc1);
            acc2 += DPP_XOR2(acc2); acc3 += DPP_XOR2(acc3);
            float ab = (s & 1) ? acc1 : acc0;
            float cd = (s & 1) ? acc3 : acc2;
            float se = (s & 2) ? cd : ab;
            S[64 + lane] = b_own * __builtin_amdgcn_rcpf(se);   // V[lane]
        }
        __syncthreads();
    }

    // ---- score = sum_ij u_i K_ij v_j sim_ij ----
    // sim = 1 + ln(K)/20 = 1 + log2(K)*(ln2/20), recomputed from Kr (no S kept)
    {
        float4 u4 = *(const float4*)&S[4 * g];           // U[4g..4g+3]
        const float4* V4 = (const float4*)&S[64 + 16 * s];
        float4 x0 = V4[0], x1 = V4[1], x2 = V4[2], x3 = V4[3];
        float vj[16] = {x0.x, x0.y, x0.z, x0.w, x1.x, x1.y, x1.z, x1.w,
                        x2.x, x2.y, x2.z, x2.w, x3.x, x3.y, x3.z, x3.w};
        float uk[4] = {u4.x, u4.y, u4.z, u4.w};
        const float c = 0.69314718056f / 20.0f;
        float p = 0.0f;
#pragma unroll
        for (int k = 0; k < 4; ++k) {
            float rs = 0.0f;
#pragma unroll
            for (int j = 0; j < 16; ++j) {
                float kk = Kr[k][j];
                float sv = fmaf(__log2f(kk), c, 1.0f);   // sim_ij
                rs = fmaf(kk * sv, vj[j], rs);
            }
            p = fmaf(uk[k], rs, p);
        }
        float tot = waveReduceSum(p);
        if (lane == 0) out[b] = tot * (TEMP / (float)N);
    }
}

extern "C" void kernel_launch(void* const* d_in, const int* in_sizes, int n_in,
                              void* d_out, int out_size, void* d_ws, size_t ws_size,
                              hipStream_t stream) {
    const float* sim = (const float*)d_in[0];
    const float* w1  = (const float*)d_in[1];
    const float* w2  = (const float*)d_in[2];
    float* out       = (float*)d_out;
    const int B = in_sizes[0] / (N * N);   // 1500
    emd_tile<<<B, 64, 0, stream>>>(sim, w1, w2, out, B);
}